// Round 1
// baseline (484.727 us; speedup 1.0000x reference)
//
#include <hip/hip_runtime.h>

// CrossAttention: B=8, N1=N2=2048, D=512
//  q    = in1 @ W^T + b                  (split-bf16 x3 MFMA)   -> q_hi/q_lo
//  S    = q @ in2^T                      (split-bf16 x3 MFMA)   -> fp32 scores (ws)
//  P    = softmax_rows(S)                (fp32 math)            -> bf16, normalized (ws)
//  out1 = P @ in2                        (bf16 MFMA)
//  out2 = P^T @ in1                      (bf16 MFMA)
// Split-bf16 needed because logits have std ~22.6 (unscaled) and near-one-hot
// softmax amplifies bf16's ~0.2 logit error past the 0.204 absmax threshold.

#define BM 128
#define BN 128
#define BK 32
#define TSTR 40  // padded LDS stride (shorts) for transpose-staged tiles

typedef __bf16 bf16x8 __attribute__((ext_vector_type(8)));
typedef short s8v __attribute__((ext_vector_type(8)));
typedef float floatx4 __attribute__((ext_vector_type(4)));

union U8 { s8v v; unsigned short u[8]; };

__device__ __forceinline__ unsigned short f2bf(float x) {
    unsigned u = __float_as_uint(x);
    return (unsigned short)((u + 0x7fffu + ((u >> 16) & 1u)) >> 16);  // RNE
}
__device__ __forceinline__ float bf2f(unsigned short s) {
    return __uint_as_float(((unsigned)s) << 16);
}
__device__ __forceinline__ floatx4 mfma_bf16(bf16x8 a, bf16x8 b, floatx4 c) {
    return __builtin_amdgcn_mfma_f32_16x16x32_bf16(a, b, c, 0, 0, 0);
}
__device__ __forceinline__ bf16x8 ldsf(const unsigned short* p) {
    return *(const bf16x8*)p;
}
__device__ __forceinline__ void split4(float4 f, unsigned short* h, unsigned short* l) {
    h[0] = f2bf(f.x); l[0] = f2bf(f.x - bf2f(h[0]));
    h[1] = f2bf(f.y); l[1] = f2bf(f.y - bf2f(h[1]));
    h[2] = f2bf(f.z); l[2] = f2bf(f.z - bf2f(h[2]));
    h[3] = f2bf(f.w); l[3] = f2bf(f.w - bf2f(h[3]));
}

// ---------------- K1: q = in1 @ W^T + bias, store split bf16 planes ----------
__global__ __launch_bounds__(256) void k_qgemm(
    const float* __restrict__ A, const float* __restrict__ W,
    const float* __restrict__ bias,
    unsigned short* __restrict__ q_hi, unsigned short* __restrict__ q_lo)
{
    __shared__ unsigned short Ah[BM * BK], Al[BM * BK], Bh[BN * BK], Bl[BN * BK];
    const int tid = threadIdx.x;
    const int lane = tid & 63, wave = tid >> 6;
    const int wM = (wave >> 1) * 64, wN = (wave & 1) * 64;
    const int lrow = lane & 15, kq = lane >> 4;
    const int r0 = blockIdx.y * BM;  // flattened (b,n) rows
    const int c0 = blockIdx.x * BN;  // output feature o
    const int srow = tid >> 1, scol = (tid & 1) * 16;

    floatx4 acc[4][4];
#pragma unroll
    for (int i = 0; i < 4; i++)
#pragma unroll
        for (int j = 0; j < 4; j++) acc[i][j] = (floatx4){0.f, 0.f, 0.f, 0.f};

    for (int k0 = 0; k0 < 512; k0 += BK) {
        {   // stage A (split fp32 -> hi/lo)
            const float* src = A + (size_t)(r0 + srow) * 512 + k0 + scol;
            float4 v0 = *(const float4*)(src);
            float4 v1 = *(const float4*)(src + 4);
            float4 v2 = *(const float4*)(src + 8);
            float4 v3 = *(const float4*)(src + 12);
            U8 h0, h1, l0, l1;
            split4(v0, &h0.u[0], &l0.u[0]); split4(v1, &h0.u[4], &l0.u[4]);
            split4(v2, &h1.u[0], &l1.u[0]); split4(v3, &h1.u[4], &l1.u[4]);
            *(s8v*)&Ah[srow * BK + scol] = h0.v; *(s8v*)&Ah[srow * BK + scol + 8] = h1.v;
            *(s8v*)&Al[srow * BK + scol] = l0.v; *(s8v*)&Al[srow * BK + scol + 8] = l1.v;
        }
        {   // stage B (split) from W rows = output cols
            const float* src = W + (size_t)(c0 + srow) * 512 + k0 + scol;
            float4 v0 = *(const float4*)(src);
            float4 v1 = *(const float4*)(src + 4);
            float4 v2 = *(const float4*)(src + 8);
            float4 v3 = *(const float4*)(src + 12);
            U8 h0, h1, l0, l1;
            split4(v0, &h0.u[0], &l0.u[0]); split4(v1, &h0.u[4], &l0.u[4]);
            split4(v2, &h1.u[0], &l1.u[0]); split4(v3, &h1.u[4], &l1.u[4]);
            *(s8v*)&Bh[srow * BK + scol] = h0.v; *(s8v*)&Bh[srow * BK + scol + 8] = h1.v;
            *(s8v*)&Bl[srow * BK + scol] = l0.v; *(s8v*)&Bl[srow * BK + scol + 8] = l1.v;
        }
        __syncthreads();
        bf16x8 ah[4], al[4], bh[4], bl[4];
#pragma unroll
        for (int i = 0; i < 4; i++) {
            const int ra = (wM + i * 16 + lrow) * BK + kq * 8;
            const int rb = (wN + i * 16 + lrow) * BK + kq * 8;
            ah[i] = ldsf(&Ah[ra]); al[i] = ldsf(&Al[ra]);
            bh[i] = ldsf(&Bh[rb]); bl[i] = ldsf(&Bl[rb]);
        }
#pragma unroll
        for (int mi = 0; mi < 4; mi++)
#pragma unroll
            for (int ni = 0; ni < 4; ni++) {
                floatx4 c = acc[mi][ni];
                c = mfma_bf16(ah[mi], bh[ni], c);
                c = mfma_bf16(ah[mi], bl[ni], c);
                c = mfma_bf16(al[mi], bh[ni], c);
                acc[mi][ni] = c;
            }
        __syncthreads();
    }
#pragma unroll
    for (int ni = 0; ni < 4; ni++) {
        const int col = c0 + wN + ni * 16 + lrow;
        const float bv = bias[col];
#pragma unroll
        for (int mi = 0; mi < 4; mi++) {
            const int row = r0 + wM + mi * 16 + kq * 4;
#pragma unroll
            for (int r = 0; r < 4; r++) {
                const float qv = acc[mi][ni][r] + bv;
                const unsigned short h = f2bf(qv);
                const size_t off = (size_t)(row + r) * 512 + col;
                q_hi[off] = h;
                q_lo[off] = f2bf(qv - bf2f(h));
            }
        }
    }
}

// ---------------- K2: S = q @ in2^T (split x split, fp32 out) ----------------
__global__ __launch_bounds__(256) void k_scores(
    const unsigned short* __restrict__ q_hi, const unsigned short* __restrict__ q_lo,
    const float* __restrict__ Kin, float* __restrict__ S)
{
    __shared__ unsigned short Ah[BM * BK], Al[BM * BK], Bh[BN * BK], Bl[BN * BK];
    const int bz = blockIdx.z;
    const unsigned short* qh = q_hi + (size_t)bz * 2048 * 512;
    const unsigned short* ql = q_lo + (size_t)bz * 2048 * 512;
    const float* Kp = Kin + (size_t)bz * 2048 * 512;
    float* Sp = S + (size_t)bz * 2048 * 2048;

    const int tid = threadIdx.x;
    const int lane = tid & 63, wave = tid >> 6;
    const int wM = (wave >> 1) * 64, wN = (wave & 1) * 64;
    const int lrow = lane & 15, kq = lane >> 4;
    const int r0 = blockIdx.y * BM;  // query rows
    const int c0 = blockIdx.x * BN;  // key cols
    const int srow = tid >> 1, scol = (tid & 1) * 16;

    floatx4 acc[4][4];
#pragma unroll
    for (int i = 0; i < 4; i++)
#pragma unroll
        for (int j = 0; j < 4; j++) acc[i][j] = (floatx4){0.f, 0.f, 0.f, 0.f};

    for (int k0 = 0; k0 < 512; k0 += BK) {
        {   // stage A: direct copy of q planes
            const unsigned short* sh = qh + (size_t)(r0 + srow) * 512 + k0 + scol;
            const unsigned short* sl = ql + (size_t)(r0 + srow) * 512 + k0 + scol;
            *(s8v*)&Ah[srow * BK + scol] = *(const s8v*)sh;
            *(s8v*)&Ah[srow * BK + scol + 8] = *(const s8v*)(sh + 8);
            *(s8v*)&Al[srow * BK + scol] = *(const s8v*)sl;
            *(s8v*)&Al[srow * BK + scol + 8] = *(const s8v*)(sl + 8);
        }
        {   // stage B: split keys
            const float* src = Kp + (size_t)(c0 + srow) * 512 + k0 + scol;
            float4 v0 = *(const float4*)(src);
            float4 v1 = *(const float4*)(src + 4);
            float4 v2 = *(const float4*)(src + 8);
            float4 v3 = *(const float4*)(src + 12);
            U8 h0, h1, l0, l1;
            split4(v0, &h0.u[0], &l0.u[0]); split4(v1, &h0.u[4], &l0.u[4]);
            split4(v2, &h1.u[0], &l1.u[0]); split4(v3, &h1.u[4], &l1.u[4]);
            *(s8v*)&Bh[srow * BK + scol] = h0.v; *(s8v*)&Bh[srow * BK + scol + 8] = h1.v;
            *(s8v*)&Bl[srow * BK + scol] = l0.v; *(s8v*)&Bl[srow * BK + scol + 8] = l1.v;
        }
        __syncthreads();
        bf16x8 ah[4], al[4], bh[4], bl[4];
#pragma unroll
        for (int i = 0; i < 4; i++) {
            const int ra = (wM + i * 16 + lrow) * BK + kq * 8;
            const int rb = (wN + i * 16 + lrow) * BK + kq * 8;
            ah[i] = ldsf(&Ah[ra]); al[i] = ldsf(&Al[ra]);
            bh[i] = ldsf(&Bh[rb]); bl[i] = ldsf(&Bl[rb]);
        }
#pragma unroll
        for (int mi = 0; mi < 4; mi++)
#pragma unroll
            for (int ni = 0; ni < 4; ni++) {
                floatx4 c = acc[mi][ni];
                c = mfma_bf16(ah[mi], bh[ni], c);
                c = mfma_bf16(ah[mi], bl[ni], c);
                c = mfma_bf16(al[mi], bh[ni], c);
                acc[mi][ni] = c;
            }
        __syncthreads();
    }
#pragma unroll
    for (int mi = 0; mi < 4; mi++)
#pragma unroll
        for (int ni = 0; ni < 4; ni++) {
            const int row = r0 + wM + mi * 16 + kq * 4;
            const int col = c0 + wN + ni * 16 + lrow;
            float* dst = Sp + (size_t)row * 2048 + col;
#pragma unroll
            for (int r = 0; r < 4; r++) dst[(size_t)r * 2048] = acc[mi][ni][r];
        }
}

// ---------------- K3: row softmax, write normalized bf16 P -------------------
__global__ __launch_bounds__(256) void k_softmax(const float* __restrict__ S,
                                                 unsigned short* __restrict__ P)
{
    const int row = blockIdx.x;
    const float* s = S + (size_t)row * 2048;
    unsigned short* p = P + (size_t)row * 2048;
    const int tid = threadIdx.x;
    const int lane = tid & 63, wave = tid >> 6;

    float4 v0 = *(const float4*)(s + tid * 8);
    float4 v1 = *(const float4*)(s + tid * 8 + 4);
    float m = fmaxf(fmaxf(fmaxf(v0.x, v0.y), fmaxf(v0.z, v0.w)),
                    fmaxf(fmaxf(v1.x, v1.y), fmaxf(v1.z, v1.w)));
#pragma unroll
    for (int off = 32; off >= 1; off >>= 1) m = fmaxf(m, __shfl_down(m, off));
    __shared__ float rb[4];
    if (lane == 0) rb[wave] = m;
    __syncthreads();
    m = fmaxf(fmaxf(rb[0], rb[1]), fmaxf(rb[2], rb[3]));

    float e[8];
    e[0] = __expf(v0.x - m); e[1] = __expf(v0.y - m);
    e[2] = __expf(v0.z - m); e[3] = __expf(v0.w - m);
    e[4] = __expf(v1.x - m); e[5] = __expf(v1.y - m);
    e[6] = __expf(v1.z - m); e[7] = __expf(v1.w - m);
    float sum = ((e[0] + e[1]) + (e[2] + e[3])) + ((e[4] + e[5]) + (e[6] + e[7]));
#pragma unroll
    for (int off = 32; off >= 1; off >>= 1) sum += __shfl_down(sum, off);
    __syncthreads();  // protect rb reuse
    if (lane == 0) rb[wave] = sum;
    __syncthreads();
    const float inv = 1.0f / (((rb[0] + rb[1]) + (rb[2] + rb[3])));

    U8 w;
#pragma unroll
    for (int i = 0; i < 8; i++) w.u[i] = f2bf(e[i] * inv);
    *(s8v*)(p + tid * 8) = w.v;
}

// ---------------- K4: out1 = P @ in2 (bf16) ----------------------------------
__global__ __launch_bounds__(256) void k_out1(
    const unsigned short* __restrict__ P, const float* __restrict__ V,
    float* __restrict__ O)
{
    __shared__ unsigned short As[BM * BK];
    __shared__ unsigned short Bs[BN * TSTR];
    const int bz = blockIdx.z;
    const unsigned short* Pp = P + (size_t)bz * 2048 * 2048;
    const float* Vp = V + (size_t)bz * 2048 * 512;
    float* Op = O + (size_t)bz * 2048 * 512;

    const int tid = threadIdx.x;
    const int lane = tid & 63, wave = tid >> 6;
    const int wM = (wave >> 1) * 64, wN = (wave & 1) * 64;
    const int lrow = lane & 15, kq = lane >> 4;
    const int r0 = blockIdx.y * BM;  // query rows
    const int c0 = blockIdx.x * BN;  // d cols
    const int srow = tid >> 1, scol = (tid & 1) * 16;
    const int pl = (tid & 63) * 2, kl0 = (tid >> 6) * 8;

    floatx4 acc[4][4];
#pragma unroll
    for (int i = 0; i < 4; i++)
#pragma unroll
        for (int j = 0; j < 4; j++) acc[i][j] = (floatx4){0.f, 0.f, 0.f, 0.f};

    for (int k0 = 0; k0 < 2048; k0 += BK) {
        {   // A: direct copy of P tile [n][m]
            const unsigned short* src = Pp + (size_t)(r0 + srow) * 2048 + k0 + scol;
            *(s8v*)&As[srow * BK + scol] = *(const s8v*)src;
            *(s8v*)&As[srow * BK + scol + 8] = *(const s8v*)(src + 8);
        }
        {   // B: transpose-stage V -> Bs[d][m], register 2x8 transpose
            U8 w0, w1;
#pragma unroll
            for (int j = 0; j < 8; j++) {
                float2 g = *(const float2*)(Vp + (size_t)(k0 + kl0 + j) * 512 + c0 + pl);
                w0.u[j] = f2bf(g.x); w1.u[j] = f2bf(g.y);
            }
            *(s8v*)&Bs[pl * TSTR + kl0] = w0.v;
            *(s8v*)&Bs[(pl + 1) * TSTR + kl0] = w1.v;
        }
        __syncthreads();
        bf16x8 a[4], b[4];
#pragma unroll
        for (int i = 0; i < 4; i++) {
            a[i] = ldsf(&As[(wM + i * 16 + lrow) * BK + kq * 8]);
            b[i] = ldsf(&Bs[(wN + i * 16 + lrow) * TSTR + kq * 8]);
        }
#pragma unroll
        for (int mi = 0; mi < 4; mi++)
#pragma unroll
            for (int ni = 0; ni < 4; ni++)
                acc[mi][ni] = mfma_bf16(a[mi], b[ni], acc[mi][ni]);
        __syncthreads();
    }
#pragma unroll
    for (int mi = 0; mi < 4; mi++)
#pragma unroll
        for (int ni = 0; ni < 4; ni++) {
            const int row = r0 + wM + mi * 16 + kq * 4;
            const int col = c0 + wN + ni * 16 + lrow;
            float* dst = Op + (size_t)row * 512 + col;
#pragma unroll
            for (int r = 0; r < 4; r++) dst[(size_t)r * 512] = acc[mi][ni][r];
        }
}

// ---------------- K5: out2 = P^T @ in1 (bf16) --------------------------------
__global__ __launch_bounds__(256) void k_out2(
    const unsigned short* __restrict__ P, const float* __restrict__ X,
    float* __restrict__ O)
{
    __shared__ unsigned short As[BM * TSTR];
    __shared__ unsigned short Bs[BN * TSTR];
    const int bz = blockIdx.z;
    const unsigned short* Pp = P + (size_t)bz * 2048 * 2048;
    const float* Xp = X + (size_t)bz * 2048 * 512;
    float* Op = O + (size_t)bz * 2048 * 512;

    const int tid = threadIdx.x;
    const int lane = tid & 63, wave = tid >> 6;
    const int wM = (wave >> 1) * 64, wN = (wave & 1) * 64;
    const int lrow = lane & 15, kq = lane >> 4;
    const int r0 = blockIdx.y * BM;  // key rows m
    const int c0 = blockIdx.x * BN;  // d cols
    const int pl = (tid & 63) * 2, kl0 = (tid >> 6) * 8;

    floatx4 acc[4][4];
#pragma unroll
    for (int i = 0; i < 4; i++)
#pragma unroll
        for (int j = 0; j < 4; j++) acc[i][j] = (floatx4){0.f, 0.f, 0.f, 0.f};

    for (int k0 = 0; k0 < 2048; k0 += BK) {
        {   // A: transpose-stage P -> As[m][n]
            U8 w0, w1;
#pragma unroll
            for (int j = 0; j < 8; j++) {
                const unsigned g =
                    *(const unsigned*)(Pp + (size_t)(k0 + kl0 + j) * 2048 + r0 + pl);
                w0.u[j] = (unsigned short)(g & 0xffffu);
                w1.u[j] = (unsigned short)(g >> 16);
            }
            *(s8v*)&As[pl * TSTR + kl0] = w0.v;
            *(s8v*)&As[(pl + 1) * TSTR + kl0] = w1.v;
        }
        {   // B: transpose-stage in1 -> Bs[d][n]
            U8 w0, w1;
#pragma unroll
            for (int j = 0; j < 8; j++) {
                float2 g = *(const float2*)(Xp + (size_t)(k0 + kl0 + j) * 512 + c0 + pl);
                w0.u[j] = f2bf(g.x); w1.u[j] = f2bf(g.y);
            }
            *(s8v*)&Bs[pl * TSTR + kl0] = w0.v;
            *(s8v*)&Bs[(pl + 1) * TSTR + kl0] = w1.v;
        }
        __syncthreads();
        bf16x8 a[4], b[4];
#pragma unroll
        for (int i = 0; i < 4; i++) {
            a[i] = ldsf(&As[(wM + i * 16 + lrow) * TSTR + kq * 8]);
            b[i] = ldsf(&Bs[(wN + i * 16 + lrow) * TSTR + kq * 8]);
        }
#pragma unroll
        for (int mi = 0; mi < 4; mi++)
#pragma unroll
            for (int ni = 0; ni < 4; ni++)
                acc[mi][ni] = mfma_bf16(a[mi], b[ni], acc[mi][ni]);
        __syncthreads();
    }
#pragma unroll
    for (int mi = 0; mi < 4; mi++)
#pragma unroll
        for (int ni = 0; ni < 4; ni++) {
            const int row = r0 + wM + mi * 16 + kq * 4;
            const int col = c0 + wN + ni * 16 + lrow;
            float* dst = Op + (size_t)row * 512 + col;
#pragma unroll
            for (int r = 0; r < 4; r++) dst[(size_t)r * 512] = acc[mi][ni][r];
        }
}

extern "C" void kernel_launch(void* const* d_in, const int* in_sizes, int n_in,
                              void* d_out, int out_size, void* d_ws, size_t ws_size,
                              hipStream_t stream)
{
    (void)in_sizes; (void)n_in; (void)out_size; (void)ws_size;
    const float* in1 = (const float*)d_in[0];
    const float* in2 = (const float*)d_in[1];
    const float* Ww  = (const float*)d_in[2];
    const float* Wb  = (const float*)d_in[3];
    float* out = (float*)d_out;

    // workspace layout: S fp32 (128MiB) | P bf16 (64MiB) | q_hi (16MiB) | q_lo (16MiB)
    char* ws = (char*)d_ws;
    float* S            = (float*)ws;
    unsigned short* P   = (unsigned short*)(ws + 134217728ull);
    unsigned short* qhi = (unsigned short*)(ws + 134217728ull + 67108864ull);
    unsigned short* qlo = (unsigned short*)(ws + 134217728ull + 67108864ull + 16777216ull);

    k_qgemm  <<<dim3(4, 128, 1), 256, 0, stream>>>(in1, Ww, Wb, qhi, qlo);
    k_scores <<<dim3(16, 16, 8), 256, 0, stream>>>(qhi, qlo, in2, S);
    k_softmax<<<dim3(16384, 1, 1), 256, 0, stream>>>(S, P);
    k_out1   <<<dim3(4, 16, 8), 256, 0, stream>>>(P, in2, out);
    k_out2   <<<dim3(4, 16, 8), 256, 0, stream>>>(P, in1, out + 8388608);
}

// Round 2
// 395.511 us; speedup vs baseline: 1.2256x; 1.2256x over previous
//
#include <hip/hip_runtime.h>

// CrossAttention B=8, N1=N2=2048, D=512 — all-fp16 MFMA pipeline.
//  prep : in1,in2,W -> fp16 (row-major) ; in2^T, in1^T -> fp16 [d][n]
//  q    = in1 @ W^T + b      (fp16 MFMA, gld16 staging)  -> q16
//  S    = q @ in2^T          (fp16 MFMA, gld16)          -> fp32 (half-batch, reused)
//  P    = softmax(S)         (fp32 math)                 -> fp16
//  out1 = P @ in2            (fp16 MFMA, gld16 both)
//  out2 = P^T @ in1          (fp16 MFMA, A reg-transposed, B gld16)
// fp16 (11-bit mantissa) keeps logit error ~0.007 (bf16 would be ~0.18 and
// fails); P in fp16 cuts the round-1-dominant weight-quantization error 8x.

#define TSTR 40  // padded LDS stride (halves) for the one transposed-staged tile

typedef _Float16 f16x8 __attribute__((ext_vector_type(8)));
typedef float floatx4 __attribute__((ext_vector_type(4)));
typedef __attribute__((address_space(1))) const void* gptr_t;
typedef __attribute__((address_space(3))) void* lptr_t;

union F8 { f16x8 v; _Float16 h[8]; unsigned short u[8]; };

__device__ __forceinline__ void gld16(const void* g, void* l) {
    __builtin_amdgcn_global_load_lds((gptr_t)g, (lptr_t)l, 16, 0, 0);
}
__device__ __forceinline__ floatx4 mfma16(f16x8 a, f16x8 b, floatx4 c) {
    return __builtin_amdgcn_mfma_f32_16x16x32_f16(a, b, c, 0, 0, 0);
}

// ---------------- prep: fp32 -> fp16 elementwise -----------------------------
__global__ __launch_bounds__(256) void k_cvt(const float* __restrict__ src,
                                             _Float16* __restrict__ dst)
{
    const size_t i = ((size_t)blockIdx.x * 256 + threadIdx.x) * 8;
    float4 a = *(const float4*)(src + i);
    float4 b = *(const float4*)(src + i + 4);
    F8 w;
    w.h[0] = (_Float16)a.x; w.h[1] = (_Float16)a.y;
    w.h[2] = (_Float16)a.z; w.h[3] = (_Float16)a.w;
    w.h[4] = (_Float16)b.x; w.h[5] = (_Float16)b.y;
    w.h[6] = (_Float16)b.z; w.h[7] = (_Float16)b.w;
    *(f16x8*)(dst + i) = w.v;
}

// ---------------- prep: [b][n][512] fp32 -> [b][512][n] fp16 -----------------
__global__ __launch_bounds__(256) void k_trans(const float* __restrict__ src,
                                               _Float16* __restrict__ dst)
{
    const int b = blockIdx.z;
    const int d0 = blockIdx.x * 128, n0 = blockIdx.y * 32;
    const float* Sp = src + (size_t)b * 2048 * 512;
    _Float16* Dp = dst + (size_t)b * 512 * 2048;
    const int t = threadIdx.x, i = t & 63, jn = t >> 6;
    const int d = d0 + 2 * i, n = n0 + jn * 8;
    F8 w0, w1;
#pragma unroll
    for (int j = 0; j < 8; j++) {
        float2 g = *(const float2*)(Sp + (size_t)(n + j) * 512 + d);
        w0.h[j] = (_Float16)g.x; w1.h[j] = (_Float16)g.y;
    }
    *(f16x8*)(Dp + (size_t)d * 2048 + n) = w0.v;
    *(f16x8*)(Dp + (size_t)(d + 1) * 2048 + n) = w1.v;
}

// ---------------- K1: q = in1 @ W^T + bias (fp16) ----------------------------
__global__ __launch_bounds__(256) void k_qgemm16(
    const _Float16* __restrict__ A, const _Float16* __restrict__ W,
    const float* __restrict__ bias, _Float16* __restrict__ q)
{
    __shared__ __align__(16) _Float16 As[128 * 32], Bs[128 * 32];
    const int tid = threadIdx.x;
    const int lane = tid & 63, wave = tid >> 6;
    const int wM = (wave >> 1) * 64, wN = (wave & 1) * 64;
    const int lrow = lane & 15, kq = lane >> 4;
    const int r0 = blockIdx.y * 128, c0 = blockIdx.x * 128;
    const int crow = tid >> 2, cc = (tid & 3) * 16;

    const char* gA = (const char*)(A + (size_t)(r0 + crow) * 512) + cc;
    const char* gB = (const char*)(W + (size_t)(c0 + crow) * 512) + cc;
    char* lA = (char*)As + tid * 16;
    char* lB = (char*)Bs + tid * 16;

    floatx4 acc[4][4];
#pragma unroll
    for (int i = 0; i < 4; i++)
#pragma unroll
        for (int j = 0; j < 4; j++) acc[i][j] = (floatx4){0.f, 0.f, 0.f, 0.f};

    for (int k0 = 0; k0 < 512; k0 += 32) {
        gld16(gA, lA); gld16(gA + 64 * 1024, lA + 4096);
        gld16(gB, lB); gld16(gB + 64 * 1024, lB + 4096);
        gA += 64; gB += 64;
        __syncthreads();
        f16x8 a[4], b[4];
#pragma unroll
        for (int i = 0; i < 4; i++) {
            a[i] = *(const f16x8*)&As[(wM + i * 16 + lrow) * 32 + kq * 8];
            b[i] = *(const f16x8*)&Bs[(wN + i * 16 + lrow) * 32 + kq * 8];
        }
#pragma unroll
        for (int mi = 0; mi < 4; mi++)
#pragma unroll
            for (int ni = 0; ni < 4; ni++)
                acc[mi][ni] = mfma16(a[mi], b[ni], acc[mi][ni]);
        __syncthreads();
    }
#pragma unroll
    for (int ni = 0; ni < 4; ni++) {
        const int col = c0 + wN + ni * 16 + lrow;
        const float bv = bias[col];
#pragma unroll
        for (int mi = 0; mi < 4; mi++) {
            const int row = r0 + wM + mi * 16 + kq * 4;
#pragma unroll
            for (int r = 0; r < 4; r++)
                q[(size_t)(row + r) * 512 + col] = (_Float16)(acc[mi][ni][r] + bv);
        }
    }
}

// ---------------- K2: S = q @ in2^T (fp16 MFMA, fp32 out) --------------------
__global__ __launch_bounds__(256) void k_scores16(
    const _Float16* __restrict__ q, const _Float16* __restrict__ k,
    float* __restrict__ S)
{
    __shared__ __align__(16) _Float16 As[128 * 32], Bs[128 * 32];
    const int tid = threadIdx.x;
    const int lane = tid & 63, wave = tid >> 6;
    const int wM = (wave >> 1) * 64, wN = (wave & 1) * 64;
    const int lrow = lane & 15, kq = lane >> 4;
    const int bz = blockIdx.z;
    const int r0 = blockIdx.y * 128, c0 = blockIdx.x * 128;
    const _Float16* qp = q + (size_t)bz * 2048 * 512;
    const _Float16* kp = k + (size_t)bz * 2048 * 512;
    float* Sp = S + (size_t)bz * 2048 * 2048;
    const int crow = tid >> 2, cc = (tid & 3) * 16;

    const char* gA = (const char*)(qp + (size_t)(r0 + crow) * 512) + cc;
    const char* gB = (const char*)(kp + (size_t)(c0 + crow) * 512) + cc;
    char* lA = (char*)As + tid * 16;
    char* lB = (char*)Bs + tid * 16;

    floatx4 acc[4][4];
#pragma unroll
    for (int i = 0; i < 4; i++)
#pragma unroll
        for (int j = 0; j < 4; j++) acc[i][j] = (floatx4){0.f, 0.f, 0.f, 0.f};

    for (int k0 = 0; k0 < 512; k0 += 32) {
        gld16(gA, lA); gld16(gA + 64 * 1024, lA + 4096);
        gld16(gB, lB); gld16(gB + 64 * 1024, lB + 4096);
        gA += 64; gB += 64;
        __syncthreads();
        f16x8 a[4], b[4];
#pragma unroll
        for (int i = 0; i < 4; i++) {
            a[i] = *(const f16x8*)&As[(wM + i * 16 + lrow) * 32 + kq * 8];
            b[i] = *(const f16x8*)&Bs[(wN + i * 16 + lrow) * 32 + kq * 8];
        }
#pragma unroll
        for (int mi = 0; mi < 4; mi++)
#pragma unroll
            for (int ni = 0; ni < 4; ni++)
                acc[mi][ni] = mfma16(a[mi], b[ni], acc[mi][ni]);
        __syncthreads();
    }
#pragma unroll
    for (int mi = 0; mi < 4; mi++)
#pragma unroll
        for (int ni = 0; ni < 4; ni++) {
            const int row = r0 + wM + mi * 16 + kq * 4;
            const int col = c0 + wN + ni * 16 + lrow;
            float* dst = Sp + (size_t)row * 2048 + col;
#pragma unroll
            for (int r = 0; r < 4; r++) dst[(size_t)r * 2048] = acc[mi][ni][r];
        }
}

// ---------------- K3: row softmax, fp32 in, fp16 out -------------------------
__global__ __launch_bounds__(256) void k_softmax(const float* __restrict__ S,
                                                 _Float16* __restrict__ P)
{
    const int row = blockIdx.x;
    const float* s = S + (size_t)row * 2048;
    _Float16* p = P + (size_t)row * 2048;
    const int tid = threadIdx.x;
    const int lane = tid & 63, wave = tid >> 6;

    float4 v0 = *(const float4*)(s + tid * 8);
    float4 v1 = *(const float4*)(s + tid * 8 + 4);
    float m = fmaxf(fmaxf(fmaxf(v0.x, v0.y), fmaxf(v0.z, v0.w)),
                    fmaxf(fmaxf(v1.x, v1.y), fmaxf(v1.z, v1.w)));
#pragma unroll
    for (int off = 32; off >= 1; off >>= 1) m = fmaxf(m, __shfl_down(m, off));
    __shared__ float rb[4];
    if (lane == 0) rb[wave] = m;
    __syncthreads();
    m = fmaxf(fmaxf(rb[0], rb[1]), fmaxf(rb[2], rb[3]));

    float e[8];
    e[0] = __expf(v0.x - m); e[1] = __expf(v0.y - m);
    e[2] = __expf(v0.z - m); e[3] = __expf(v0.w - m);
    e[4] = __expf(v1.x - m); e[5] = __expf(v1.y - m);
    e[6] = __expf(v1.z - m); e[7] = __expf(v1.w - m);
    float sum = ((e[0] + e[1]) + (e[2] + e[3])) + ((e[4] + e[5]) + (e[6] + e[7]));
#pragma unroll
    for (int off = 32; off >= 1; off >>= 1) sum += __shfl_down(sum, off);
    __syncthreads();
    if (lane == 0) rb[wave] = sum;
    __syncthreads();
    const float inv = 1.0f / (((rb[0] + rb[1]) + (rb[2] + rb[3])));

    F8 w;
#pragma unroll
    for (int i = 0; i < 8; i++) w.h[i] = (_Float16)(e[i] * inv);
    *(f16x8*)(p + tid * 8) = w.v;
}

// ---------------- K4: out1 = P @ in2  (A=P rows, B=Vt rows, both gld16) ------
__global__ __launch_bounds__(256) void k_out1(
    const _Float16* __restrict__ P, const _Float16* __restrict__ Vt,
    float* __restrict__ O)
{
    __shared__ __align__(16) _Float16 As[128 * 32], Bs[128 * 32];
    const int bz = blockIdx.z;
    const _Float16* Pp = P + (size_t)bz * 2048 * 2048;
    const _Float16* Vp = Vt + (size_t)bz * 512 * 2048;
    float* Op = O + (size_t)bz * 2048 * 512;

    const int tid = threadIdx.x;
    const int lane = tid & 63, wave = tid >> 6;
    const int wM = (wave >> 1) * 64, wN = (wave & 1) * 64;
    const int lrow = lane & 15, kq = lane >> 4;
    const int r0 = blockIdx.y * 128, c0 = blockIdx.x * 128;
    const int crow = tid >> 2, cc = (tid & 3) * 16;

    const char* gA = (const char*)(Pp + (size_t)(r0 + crow) * 2048) + cc;
    const char* gB = (const char*)(Vp + (size_t)(c0 + crow) * 2048) + cc;
    char* lA = (char*)As + tid * 16;
    char* lB = (char*)Bs + tid * 16;

    floatx4 acc[4][4];
#pragma unroll
    for (int i = 0; i < 4; i++)
#pragma unroll
        for (int j = 0; j < 4; j++) acc[i][j] = (floatx4){0.f, 0.f, 0.f, 0.f};

    for (int k0 = 0; k0 < 2048; k0 += 32) {
        gld16(gA, lA); gld16(gA + 64 * 4096, lA + 4096);
        gld16(gB, lB); gld16(gB + 64 * 4096, lB + 4096);
        gA += 64; gB += 64;
        __syncthreads();
        f16x8 a[4], b[4];
#pragma unroll
        for (int i = 0; i < 4; i++) {
            a[i] = *(const f16x8*)&As[(wM + i * 16 + lrow) * 32 + kq * 8];
            b[i] = *(const f16x8*)&Bs[(wN + i * 16 + lrow) * 32 + kq * 8];
        }
#pragma unroll
        for (int mi = 0; mi < 4; mi++)
#pragma unroll
            for (int ni = 0; ni < 4; ni++)
                acc[mi][ni] = mfma16(a[mi], b[ni], acc[mi][ni]);
        __syncthreads();
    }
#pragma unroll
    for (int mi = 0; mi < 4; mi++)
#pragma unroll
        for (int ni = 0; ni < 4; ni++) {
            const int row = r0 + wM + mi * 16 + kq * 4;
            const int col = c0 + wN + ni * 16 + lrow;
            float* dst = Op + (size_t)row * 512 + col;
#pragma unroll
            for (int r = 0; r < 4; r++) dst[(size_t)r * 512] = acc[mi][ni][r];
        }
}

// ---------------- K5: out2 = P^T @ in1 (A=P reg-transposed, B=Xt gld16) ------
__global__ __launch_bounds__(256) void k_out2(
    const _Float16* __restrict__ P, const _Float16* __restrict__ Xt,
    float* __restrict__ O)
{
    __shared__ __align__(16) _Float16 As[128 * TSTR];
    __shared__ __align__(16) _Float16 Bs[128 * 32];
    const int bz = blockIdx.z;
    const _Float16* Pp = P + (size_t)bz * 2048 * 2048;
    const _Float16* Xp = Xt + (size_t)bz * 512 * 2048;
    float* Op = O + (size_t)bz * 2048 * 512;

    const int tid = threadIdx.x;
    const int lane = tid & 63, wave = tid >> 6;
    const int wM = (wave >> 1) * 64, wN = (wave & 1) * 64;
    const int lrow = lane & 15, kq = lane >> 4;
    const int r0 = blockIdx.y * 128, c0 = blockIdx.x * 128;
    const int pl = (tid & 63) * 2, kl0 = (tid >> 6) * 8;
    const int crow = tid >> 2, cc = (tid & 3) * 16;

    const char* gB = (const char*)(Xp + (size_t)(c0 + crow) * 2048) + cc;
    char* lB = (char*)Bs + tid * 16;

    floatx4 acc[4][4];
#pragma unroll
    for (int i = 0; i < 4; i++)
#pragma unroll
        for (int j = 0; j < 4; j++) acc[i][j] = (floatx4){0.f, 0.f, 0.f, 0.f};

    for (int k0 = 0; k0 < 2048; k0 += 32) {
        gld16(gB, lB); gld16(gB + 64 * 4096, lB + 4096);
        gB += 64;
        {   // A: transpose-stage P -> As[m][n]
            F8 w0, w1;
#pragma unroll
            for (int j = 0; j < 8; j++) {
                const unsigned g =
                    *(const unsigned*)(Pp + (size_t)(k0 + kl0 + j) * 2048 + r0 + pl);
                w0.u[j] = (unsigned short)(g & 0xffffu);
                w1.u[j] = (unsigned short)(g >> 16);
            }
            *(f16x8*)&As[pl * TSTR + kl0] = w0.v;
            *(f16x8*)&As[(pl + 1) * TSTR + kl0] = w1.v;
        }
        __syncthreads();
        f16x8 a[4], b[4];
#pragma unroll
        for (int i = 0; i < 4; i++) {
            a[i] = *(const f16x8*)&As[(wM + i * 16 + lrow) * TSTR + kq * 8];
            b[i] = *(const f16x8*)&Bs[(wN + i * 16 + lrow) * 32 + kq * 8];
        }
#pragma unroll
        for (int mi = 0; mi < 4; mi++)
#pragma unroll
            for (int ni = 0; ni < 4; ni++)
                acc[mi][ni] = mfma16(a[mi], b[ni], acc[mi][ni]);
        __syncthreads();
    }
#pragma unroll
    for (int mi = 0; mi < 4; mi++)
#pragma unroll
        for (int ni = 0; ni < 4; ni++) {
            const int row = r0 + wM + mi * 16 + kq * 4;
            const int col = c0 + wN + ni * 16 + lrow;
            float* dst = Op + (size_t)row * 512 + col;
#pragma unroll
            for (int r = 0; r < 4; r++) dst[(size_t)r * 512] = acc[mi][ni][r];
        }
}

extern "C" void kernel_launch(void* const* d_in, const int* in_sizes, int n_in,
                              void* d_out, int out_size, void* d_ws, size_t ws_size,
                              hipStream_t stream)
{
    (void)in_sizes; (void)n_in; (void)out_size; (void)ws_size;
    const float* in1 = (const float*)d_in[0];
    const float* in2 = (const float*)d_in[1];
    const float* Ww  = (const float*)d_in[2];
    const float* Wb  = (const float*)d_in[3];
    float* out = (float*)d_out;

    // ws layout (bytes): S fp32 half-batch 64MiB | P fp16 64MiB | q16 16MiB |
    //                    x16 16MiB | k16 16MiB | vt 16MiB | xt 16MiB | w16 0.5MiB
    char* ws = (char*)d_ws;
    float*    S   = (float*)   ws;
    _Float16* P   = (_Float16*)(ws + 67108864ull);
    _Float16* q16 = (_Float16*)(ws + 134217728ull);
    _Float16* x16 = (_Float16*)(ws + 150994944ull);
    _Float16* k16 = (_Float16*)(ws + 167772160ull);
    _Float16* vt  = (_Float16*)(ws + 184549376ull);
    _Float16* xt  = (_Float16*)(ws + 201326592ull);
    _Float16* w16 = (_Float16*)(ws + 218103808ull);

    k_cvt  <<<4096, 256, 0, stream>>>(in1, x16);
    k_cvt  <<<4096, 256, 0, stream>>>(in2, k16);
    k_cvt  <<<128,  256, 0, stream>>>(Ww, w16);
    k_trans<<<dim3(4, 64, 8), 256, 0, stream>>>(in2, vt);
    k_trans<<<dim3(4, 64, 8), 256, 0, stream>>>(in1, xt);
    k_qgemm16<<<dim3(4, 128, 1), 256, 0, stream>>>(x16, w16, Wb, q16);
    for (int h = 0; h < 2; h++) {
        k_scores16<<<dim3(16, 16, 4), 256, 0, stream>>>(
            q16 + (size_t)h * 4 * 2048 * 512, k16 + (size_t)h * 4 * 2048 * 512, S);
        k_softmax<<<8192, 256, 0, stream>>>(S, P + (size_t)h * 4 * 2048 * 2048);
    }
    k_out1<<<dim3(4, 16, 8), 256, 0, stream>>>(P, vt, out);
    k_out2<<<dim3(4, 16, 8), 256, 0, stream>>>(P, xt, out + 8388608);
}

// Round 3
// 326.342 us; speedup vs baseline: 1.4853x; 1.2119x over previous
//
#include <hip/hip_runtime.h>

// CrossAttention B=8, N1=N2=2048, D=512 — all-fp16 MFMA pipeline, R3.
//  prep : in1 -> x16 (row) + xt (col) ; in2 -> k16 (row) + vt (col)   [fused]
//  q    = in1 @ W^T + b      (fp16 MFMA, BK=64, gld16+swizzle) -> q16
//  S    = q @ in2^T          (fp16 MFMA)                       -> fp32 half-batch
//  P    = softmax(S)         (fp32)                            -> fp16
//  out1 = P @ in2            (BM64xBN256, batch-XCD swizzle)
//  out2 = P^T @ in1          (same tile, A reg-transposed)
// LDS XOR swizzle (oct ^= row&7): BK=64 row stride = 128 B -> unswizzled frag
// reads are 16-way bank conflicts; swizzled = 2-way (free).

typedef _Float16 f16x8 __attribute__((ext_vector_type(8)));
typedef float floatx4 __attribute__((ext_vector_type(4)));
typedef __attribute__((address_space(1))) const void* gptr_t;
typedef __attribute__((address_space(3))) void* lptr_t;

union F8 { f16x8 v; _Float16 h[8]; unsigned short u[8]; unsigned w[4]; };

__device__ __forceinline__ void gld16(const void* g, void* l) {
    __builtin_amdgcn_global_load_lds((gptr_t)g, (lptr_t)l, 16, 0, 0);
}
__device__ __forceinline__ floatx4 mfma16(f16x8 a, f16x8 b, floatx4 c) {
    return __builtin_amdgcn_mfma_f32_16x16x32_f16(a, b, c, 0, 0, 0);
}

// Stage ROWS x 64 fp16 tile (row-major, ld = ldg halves) into LDS with XOR
// swizzle: LDS chunk (row, s) holds global oct (s ^ (row&7)).
template <int ROWS>
__device__ __forceinline__ void stage64(const _Float16* g, int ldg,
                                        _Float16* lds, int tid) {
#pragma unroll
    for (int c = 0; c < (ROWS * 8) / 256; ++c) {
        const int q = c * 256 + tid;
        const int row = q >> 3;
        const int oct = (q & 7) ^ (row & 7);
        gld16(g + (size_t)row * ldg + oct * 8, lds + q * 8);
    }
}
__device__ __forceinline__ f16x8 ldfrag(const _Float16* lds, int row, int j) {
    return *(const f16x8*)&lds[row * 64 + ((j ^ (row & 7)) << 3)];
}

// ---------------- prep: fp32 [b][n][512] -> row fp16 + col fp16 --------------
__global__ __launch_bounds__(256) void k_prep(const float* __restrict__ src,
                                              _Float16* __restrict__ rowo,
                                              _Float16* __restrict__ colo)
{
    const int b = blockIdx.z;
    const int d0 = blockIdx.x * 128, n0 = blockIdx.y * 32;
    const float* Sp = src + (size_t)b * 2048 * 512;
    _Float16* Rp = rowo + (size_t)b * 2048 * 512;
    _Float16* Cp = colo + (size_t)b * 512 * 2048;
    const int t = threadIdx.x, i = t & 63, jn = t >> 6;
    const int d = d0 + 2 * i, n = n0 + jn * 8;
    F8 w0, w1;
#pragma unroll
    for (int j = 0; j < 8; j++) {
        float2 g = *(const float2*)(Sp + (size_t)(n + j) * 512 + d);
        w0.h[j] = (_Float16)g.x; w1.h[j] = (_Float16)g.y;
        F8 r; r.h[0] = w0.h[j]; r.h[1] = w1.h[j];
        *(unsigned*)(Rp + (size_t)(n + j) * 512 + d) = r.w[0];
    }
    *(f16x8*)(Cp + (size_t)d * 2048 + n) = w0.v;
    *(f16x8*)(Cp + (size_t)(d + 1) * 2048 + n) = w1.v;
}

// ---------------- prep: fp32 -> fp16 elementwise (for W) ---------------------
__global__ __launch_bounds__(256) void k_cvt(const float* __restrict__ src,
                                             _Float16* __restrict__ dst)
{
    const size_t i = ((size_t)blockIdx.x * 256 + threadIdx.x) * 8;
    float4 a = *(const float4*)(src + i);
    float4 b = *(const float4*)(src + i + 4);
    F8 w;
    w.h[0] = (_Float16)a.x; w.h[1] = (_Float16)a.y;
    w.h[2] = (_Float16)a.z; w.h[3] = (_Float16)a.w;
    w.h[4] = (_Float16)b.x; w.h[5] = (_Float16)b.y;
    w.h[6] = (_Float16)b.z; w.h[7] = (_Float16)b.w;
    *(f16x8*)(dst + i) = w.v;
}

// ---------------- K1: q = in1 @ W^T + bias (128x128, BK=64) ------------------
__global__ __launch_bounds__(256, 4) void k_qgemm16(
    const _Float16* __restrict__ A, const _Float16* __restrict__ W,
    const float* __restrict__ bias, _Float16* __restrict__ q)
{
    __shared__ __align__(16) _Float16 As[128 * 64], Bs[128 * 64];
    const int tid = threadIdx.x;
    const int lane = tid & 63, wave = tid >> 6;
    const int wM = (wave >> 1) * 64, wN = (wave & 1) * 64;
    const int lrow = lane & 15, kq = lane >> 4;
    const int bi = blockIdx.x;
    const int r0 = (bi >> 2) * 128, c0 = (bi & 3) * 128;

    floatx4 acc[4][4];
#pragma unroll
    for (int i = 0; i < 4; i++)
#pragma unroll
        for (int j = 0; j < 4; j++) acc[i][j] = (floatx4){0.f, 0.f, 0.f, 0.f};

    for (int k0 = 0; k0 < 512; k0 += 64) {
        stage64<128>(A + (size_t)r0 * 512 + k0, 512, As, tid);
        stage64<128>(W + (size_t)c0 * 512 + k0, 512, Bs, tid);
        __syncthreads();
#pragma unroll
        for (int ks = 0; ks < 2; ks++) {
            f16x8 a[4], b[4];
#pragma unroll
            for (int i = 0; i < 4; i++) {
                a[i] = ldfrag(As, wM + i * 16 + lrow, ks * 4 + kq);
                b[i] = ldfrag(Bs, wN + i * 16 + lrow, ks * 4 + kq);
            }
#pragma unroll
            for (int mi = 0; mi < 4; mi++)
#pragma unroll
                for (int ni = 0; ni < 4; ni++)
                    acc[mi][ni] = mfma16(a[mi], b[ni], acc[mi][ni]);
        }
        __syncthreads();
    }
#pragma unroll
    for (int ni = 0; ni < 4; ni++) {
        const int col = c0 + wN + ni * 16 + lrow;
        const float bv = bias[col];
#pragma unroll
        for (int mi = 0; mi < 4; mi++) {
            const int row = r0 + wM + mi * 16 + kq * 4;
#pragma unroll
            for (int r = 0; r < 4; r++)
                q[(size_t)(row + r) * 512 + col] = (_Float16)(acc[mi][ni][r] + bv);
        }
    }
}

// ---------------- K2: S = q @ in2^T (128x128, BK=64, 4-batch dispatch) -------
__global__ __launch_bounds__(256, 4) void k_scores16(
    const _Float16* __restrict__ q, const _Float16* __restrict__ k,
    float* __restrict__ S)
{
    __shared__ __align__(16) _Float16 As[128 * 64], Bs[128 * 64];
    const int tid = threadIdx.x;
    const int lane = tid & 63, wave = tid >> 6;
    const int wM = (wave >> 1) * 64, wN = (wave & 1) * 64;
    const int lrow = lane & 15, kq = lane >> 4;
    const int bi = blockIdx.x;
    const int bz = bi & 3, t = bi >> 2;       // low bits = batch -> XCD locality
    const int c0 = (t & 15) * 128, r0 = (t >> 4) * 128;
    const _Float16* qp = q + (size_t)bz * 2048 * 512;
    const _Float16* kp = k + (size_t)bz * 2048 * 512;
    float* Sp = S + (size_t)bz * 2048 * 2048;

    floatx4 acc[4][4];
#pragma unroll
    for (int i = 0; i < 4; i++)
#pragma unroll
        for (int j = 0; j < 4; j++) acc[i][j] = (floatx4){0.f, 0.f, 0.f, 0.f};

    for (int k0 = 0; k0 < 512; k0 += 64) {
        stage64<128>(qp + (size_t)r0 * 512 + k0, 512, As, tid);
        stage64<128>(kp + (size_t)c0 * 512 + k0, 512, Bs, tid);
        __syncthreads();
#pragma unroll
        for (int ks = 0; ks < 2; ks++) {
            f16x8 a[4], b[4];
#pragma unroll
            for (int i = 0; i < 4; i++) {
                a[i] = ldfrag(As, wM + i * 16 + lrow, ks * 4 + kq);
                b[i] = ldfrag(Bs, wN + i * 16 + lrow, ks * 4 + kq);
            }
#pragma unroll
            for (int mi = 0; mi < 4; mi++)
#pragma unroll
                for (int ni = 0; ni < 4; ni++)
                    acc[mi][ni] = mfma16(a[mi], b[ni], acc[mi][ni]);
        }
        __syncthreads();
    }
#pragma unroll
    for (int mi = 0; mi < 4; mi++)
#pragma unroll
        for (int ni = 0; ni < 4; ni++) {
            const int row = r0 + wM + mi * 16 + kq * 4;
            const int col = c0 + wN + ni * 16 + lrow;
            float* dst = Sp + (size_t)row * 2048 + col;
#pragma unroll
            for (int r = 0; r < 4; r++) dst[(size_t)r * 2048] = acc[mi][ni][r];
        }
}

// ---------------- K3: row softmax, fp32 in, fp16 out -------------------------
__global__ __launch_bounds__(256) void k_softmax(const float* __restrict__ S,
                                                 _Float16* __restrict__ P)
{
    const int row = blockIdx.x;
    const float* s = S + (size_t)row * 2048;
    _Float16* p = P + (size_t)row * 2048;
    const int tid = threadIdx.x;
    const int lane = tid & 63, wave = tid >> 6;

    float4 v0 = *(const float4*)(s + tid * 8);
    float4 v1 = *(const float4*)(s + tid * 8 + 4);
    float m = fmaxf(fmaxf(fmaxf(v0.x, v0.y), fmaxf(v0.z, v0.w)),
                    fmaxf(fmaxf(v1.x, v1.y), fmaxf(v1.z, v1.w)));
#pragma unroll
    for (int off = 32; off >= 1; off >>= 1) m = fmaxf(m, __shfl_down(m, off));
    __shared__ float rb[4];
    if (lane == 0) rb[wave] = m;
    __syncthreads();
    m = fmaxf(fmaxf(rb[0], rb[1]), fmaxf(rb[2], rb[3]));

    float e[8];
    e[0] = __expf(v0.x - m); e[1] = __expf(v0.y - m);
    e[2] = __expf(v0.z - m); e[3] = __expf(v0.w - m);
    e[4] = __expf(v1.x - m); e[5] = __expf(v1.y - m);
    e[6] = __expf(v1.z - m); e[7] = __expf(v1.w - m);
    float sum = ((e[0] + e[1]) + (e[2] + e[3])) + ((e[4] + e[5]) + (e[6] + e[7]));
#pragma unroll
    for (int off = 32; off >= 1; off >>= 1) sum += __shfl_down(sum, off);
    __syncthreads();
    if (lane == 0) rb[wave] = sum;
    __syncthreads();
    const float inv = 1.0f / (((rb[0] + rb[1]) + (rb[2] + rb[3])));

    F8 w;
#pragma unroll
    for (int i = 0; i < 8; i++) w.h[i] = (_Float16)(e[i] * inv);
    *(f16x8*)(p + tid * 8) = w.v;
}

// ---------------- K4: out1 = P @ in2  (BM64 x BN256 x BK64) ------------------
__global__ __launch_bounds__(256, 2) void k_out1(
    const _Float16* __restrict__ P, const _Float16* __restrict__ Vt,
    float* __restrict__ O)
{
    __shared__ __align__(16) _Float16 As[64 * 64], Bs[256 * 64];
    const int tid = threadIdx.x;
    const int lane = tid & 63, wave = tid >> 6;
    const int wN = wave * 64;                  // 4 waves across BN=256
    const int lrow = lane & 15, kq = lane >> 4;
    const int bi = blockIdx.x;
    const int bz = bi & 7, t = bi >> 3;        // low bits = batch -> XCD locality
    const int c0 = (t & 1) * 256, r0 = (t >> 1) * 64;
    const _Float16* Pp = P + (size_t)bz * 2048 * 2048;
    const _Float16* Vp = Vt + (size_t)bz * 512 * 2048;
    float* Op = O + (size_t)bz * 2048 * 512;

    floatx4 acc[4][4];
#pragma unroll
    for (int i = 0; i < 4; i++)
#pragma unroll
        for (int j = 0; j < 4; j++) acc[i][j] = (floatx4){0.f, 0.f, 0.f, 0.f};

    for (int k0 = 0; k0 < 2048; k0 += 64) {
        stage64<64>(Pp + (size_t)r0 * 2048 + k0, 2048, As, tid);
        stage64<256>(Vp + (size_t)c0 * 2048 + k0, 2048, Bs, tid);
        __syncthreads();
#pragma unroll
        for (int ks = 0; ks < 2; ks++) {
            f16x8 a[4], b[4];
#pragma unroll
            for (int i = 0; i < 4; i++) {
                a[i] = ldfrag(As, i * 16 + lrow, ks * 4 + kq);
                b[i] = ldfrag(Bs, wN + i * 16 + lrow, ks * 4 + kq);
            }
#pragma unroll
            for (int mi = 0; mi < 4; mi++)
#pragma unroll
                for (int ni = 0; ni < 4; ni++)
                    acc[mi][ni] = mfma16(a[mi], b[ni], acc[mi][ni]);
        }
        __syncthreads();
    }
#pragma unroll
    for (int mi = 0; mi < 4; mi++)
#pragma unroll
        for (int ni = 0; ni < 4; ni++) {
            const int row = r0 + mi * 16 + kq * 4;
            const int col = c0 + wN + ni * 16 + lrow;
            float* dst = Op + (size_t)row * 512 + col;
#pragma unroll
            for (int r = 0; r < 4; r++) dst[(size_t)r * 512] = acc[mi][ni][r];
        }
}

// ---------------- K5: out2 = P^T @ in1 (A transpose-staged) ------------------
#define ASTR 72  // padded stride (halves) for transposed A tile
__global__ __launch_bounds__(256, 2) void k_out2(
    const _Float16* __restrict__ P, const _Float16* __restrict__ Xt,
    float* __restrict__ O)
{
    __shared__ __align__(16) _Float16 As[64 * ASTR];
    __shared__ __align__(16) _Float16 Bs[256 * 64];
    const int tid = threadIdx.x;
    const int lane = tid & 63, wave = tid >> 6;
    const int wN = wave * 64;
    const int lrow = lane & 15, kq = lane >> 4;
    const int bi = blockIdx.x;
    const int bz = bi & 7, t = bi >> 3;
    const int c0 = (t & 1) * 256, r0 = (t >> 1) * 64;   // r0 = key rows m
    const _Float16* Pp = P + (size_t)bz * 2048 * 2048;
    const _Float16* Xp = Xt + (size_t)bz * 512 * 2048;
    float* Op = O + (size_t)bz * 2048 * 512;

    const int mPair = (tid & 31) * 2;       // m column pair within tile
    const int kOct = tid >> 5;              // which k-oct (8 groups of 8)
    const int aswz = (kOct ^ (tid & 7)) << 3;  // (mPair>>1)&7 == tid&7

    floatx4 acc[4][4];
#pragma unroll
    for (int i = 0; i < 4; i++)
#pragma unroll
        for (int j = 0; j < 4; j++) acc[i][j] = (floatx4){0.f, 0.f, 0.f, 0.f};

    for (int k0 = 0; k0 < 2048; k0 += 64) {
        stage64<256>(Xp + (size_t)c0 * 2048 + k0, 2048, Bs, tid);
        {   // A: transpose-stage P[k][m] -> As[m][k], swizzled oct
            F8 w0, w1;
#pragma unroll
            for (int j = 0; j < 8; j++) {
                const unsigned g = *(const unsigned*)(
                    Pp + (size_t)(k0 + kOct * 8 + j) * 2048 + r0 + mPair);
                w0.u[j] = (unsigned short)(g & 0xffffu);
                w1.u[j] = (unsigned short)(g >> 16);
            }
            *(f16x8*)&As[mPair * ASTR + aswz] = w0.v;
            *(f16x8*)&As[(mPair + 1) * ASTR + aswz] = w1.v;
        }
        __syncthreads();
#pragma unroll
        for (int ks = 0; ks < 2; ks++) {
            f16x8 a[4], b[4];
#pragma unroll
            for (int i = 0; i < 4; i++) {
                const int m = i * 16 + lrow;
                a[i] = *(const f16x8*)&As[m * ASTR +
                                          (((ks * 4 + kq) ^ ((m >> 1) & 7)) << 3)];
                b[i] = ldfrag(Bs, wN + i * 16 + lrow, ks * 4 + kq);
            }
#pragma unroll
            for (int mi = 0; mi < 4; mi++)
#pragma unroll
                for (int ni = 0; ni < 4; ni++)
                    acc[mi][ni] = mfma16(a[mi], b[ni], acc[mi][ni]);
        }
        __syncthreads();
    }
#pragma unroll
    for (int mi = 0; mi < 4; mi++)
#pragma unroll
        for (int ni = 0; ni < 4; ni++) {
            const int row = r0 + mi * 16 + kq * 4;
            const int col = c0 + wN + ni * 16 + lrow;
            float* dst = Op + (size_t)row * 512 + col;
#pragma unroll
            for (int r = 0; r < 4; r++) dst[(size_t)r * 512] = acc[mi][ni][r];
        }
}

extern "C" void kernel_launch(void* const* d_in, const int* in_sizes, int n_in,
                              void* d_out, int out_size, void* d_ws, size_t ws_size,
                              hipStream_t stream)
{
    (void)in_sizes; (void)n_in; (void)out_size; (void)ws_size;
    const float* in1 = (const float*)d_in[0];
    const float* in2 = (const float*)d_in[1];
    const float* Ww  = (const float*)d_in[2];
    const float* Wb  = (const float*)d_in[3];
    float* out = (float*)d_out;

    char* ws = (char*)d_ws;
    float*    S   = (float*)   ws;                       // 64 MiB (half-batch)
    _Float16* P   = (_Float16*)(ws + 67108864ull);       // 64 MiB
    _Float16* q16 = (_Float16*)(ws + 134217728ull);      // 16 MiB
    _Float16* x16 = (_Float16*)(ws + 150994944ull);      // 16 MiB
    _Float16* k16 = (_Float16*)(ws + 167772160ull);      // 16 MiB
    _Float16* vt  = (_Float16*)(ws + 184549376ull);      // 16 MiB
    _Float16* xt  = (_Float16*)(ws + 201326592ull);      // 16 MiB
    _Float16* w16 = (_Float16*)(ws + 218103808ull);      // 0.5 MiB

    k_prep<<<dim3(4, 64, 8), 256, 0, stream>>>(in1, x16, xt);
    k_prep<<<dim3(4, 64, 8), 256, 0, stream>>>(in2, k16, vt);
    k_cvt <<<128, 256, 0, stream>>>(Ww, w16);
    k_qgemm16<<<512, 256, 0, stream>>>(x16, w16, Wb, q16);
    for (int h = 0; h < 2; h++) {
        k_scores16<<<1024, 256, 0, stream>>>(
            q16 + (size_t)h * 4 * 2048 * 512, k16 + (size_t)h * 4 * 2048 * 512, S);
        k_softmax<<<8192, 256, 0, stream>>>(S, P + (size_t)h * 4 * 2048 * 2048);
    }
    k_out1<<<512, 256, 0, stream>>>(P, vt, out);
    k_out2<<<512, 256, 0, stream>>>(P, xt, out + 8388608);
}

// Round 4
// 314.896 us; speedup vs baseline: 1.5393x; 1.0364x over previous
//
#include <hip/hip_runtime.h>

// CrossAttention B=8, N1=N2=2048, D=512 — all-fp16 MFMA pipeline, R4.
//  prep : in1 -> x16 (row) + xt (col) ; in2 -> k16 (row) + vt (col)
//  q    = in1 @ W^T + b   (fp16 MFMA, BK=64, gld16+swizzle) -> q16
//  S    = q @ in2^T       (fp16 MFMA)            -> fp16 logits (half-batch)
//  P    = softmax(S)      (fp32 math)            -> fp16
//  out1 = P @ in2         (BM64xBN128, 1024 blocks: latency fix vs R3's 512)
//  out2 = P^T @ in1       (same tile, A reg-transposed)
// R3 post-mortem: out1/out2 were latency-bound (2 blocks/CU, MfmaUtil 20%,
// HBM 15%) -> halve tile, double grid. S fp16: absmax invariant to P precision
// (0.0625 across bf16/fp16 P) proves logit rounding dominates; fp16 S adds
// ~0.05 worst-case, budget holds.

typedef _Float16 f16x8 __attribute__((ext_vector_type(8)));
typedef float floatx4 __attribute__((ext_vector_type(4)));
typedef __attribute__((address_space(1))) const void* gptr_t;
typedef __attribute__((address_space(3))) void* lptr_t;

union F8 { f16x8 v; _Float16 h[8]; unsigned short u[8]; unsigned w[4]; };

__device__ __forceinline__ void gld16(const void* g, void* l) {
    __builtin_amdgcn_global_load_lds((gptr_t)g, (lptr_t)l, 16, 0, 0);
}
__device__ __forceinline__ floatx4 mfma16(f16x8 a, f16x8 b, floatx4 c) {
    return __builtin_amdgcn_mfma_f32_16x16x32_f16(a, b, c, 0, 0, 0);
}

// Stage ROWS x 64 fp16 tile (row-major) into LDS with XOR swizzle:
// LDS chunk (row, s) holds global oct (s ^ (row&7)).
template <int ROWS>
__device__ __forceinline__ void stage64(const _Float16* g, int ldg,
                                        _Float16* lds, int tid) {
#pragma unroll
    for (int c = 0; c < (ROWS * 8) / 256; ++c) {
        const int q = c * 256 + tid;
        const int row = q >> 3;
        const int oct = (q & 7) ^ (row & 7);
        gld16(g + (size_t)row * ldg + oct * 8, lds + q * 8);
    }
}
__device__ __forceinline__ f16x8 ldfrag(const _Float16* lds, int row, int j) {
    return *(const f16x8*)&lds[row * 64 + ((j ^ (row & 7)) << 3)];
}

// ---------------- prep: fp32 [b][n][512] -> row fp16 + col fp16 --------------
__global__ __launch_bounds__(256) void k_prep(const float* __restrict__ src,
                                              _Float16* __restrict__ rowo,
                                              _Float16* __restrict__ colo)
{
    const int b = blockIdx.z;
    const int d0 = blockIdx.x * 128, n0 = blockIdx.y * 32;
    const float* Sp = src + (size_t)b * 2048 * 512;
    _Float16* Rp = rowo + (size_t)b * 2048 * 512;
    _Float16* Cp = colo + (size_t)b * 512 * 2048;
    const int t = threadIdx.x, i = t & 63, jn = t >> 6;
    const int d = d0 + 2 * i, n = n0 + jn * 8;
    F8 w0, w1;
#pragma unroll
    for (int j = 0; j < 8; j++) {
        float2 g = *(const float2*)(Sp + (size_t)(n + j) * 512 + d);
        w0.h[j] = (_Float16)g.x; w1.h[j] = (_Float16)g.y;
        F8 r; r.h[0] = w0.h[j]; r.h[1] = w1.h[j];
        *(unsigned*)(Rp + (size_t)(n + j) * 512 + d) = r.w[0];
    }
    *(f16x8*)(Cp + (size_t)d * 2048 + n) = w0.v;
    *(f16x8*)(Cp + (size_t)(d + 1) * 2048 + n) = w1.v;
}

// ---------------- prep: fp32 -> fp16 elementwise (for W) ---------------------
__global__ __launch_bounds__(256) void k_cvt(const float* __restrict__ src,
                                             _Float16* __restrict__ dst)
{
    const size_t i = ((size_t)blockIdx.x * 256 + threadIdx.x) * 8;
    float4 a = *(const float4*)(src + i);
    float4 b = *(const float4*)(src + i + 4);
    F8 w;
    w.h[0] = (_Float16)a.x; w.h[1] = (_Float16)a.y;
    w.h[2] = (_Float16)a.z; w.h[3] = (_Float16)a.w;
    w.h[4] = (_Float16)b.x; w.h[5] = (_Float16)b.y;
    w.h[6] = (_Float16)b.z; w.h[7] = (_Float16)b.w;
    *(f16x8*)(dst + i) = w.v;
}

// ---------------- K1: q = in1 @ W^T + bias (128x128, BK=64) ------------------
__global__ __launch_bounds__(256, 4) void k_qgemm16(
    const _Float16* __restrict__ A, const _Float16* __restrict__ W,
    const float* __restrict__ bias, _Float16* __restrict__ q)
{
    __shared__ __align__(16) _Float16 As[128 * 64], Bs[128 * 64];
    const int tid = threadIdx.x;
    const int lane = tid & 63, wave = tid >> 6;
    const int wM = (wave >> 1) * 64, wN = (wave & 1) * 64;
    const int lrow = lane & 15, kq = lane >> 4;
    const int bi = blockIdx.x;
    const int r0 = (bi >> 2) * 128, c0 = (bi & 3) * 128;

    floatx4 acc[4][4];
#pragma unroll
    for (int i = 0; i < 4; i++)
#pragma unroll
        for (int j = 0; j < 4; j++) acc[i][j] = (floatx4){0.f, 0.f, 0.f, 0.f};

    for (int k0 = 0; k0 < 512; k0 += 64) {
        stage64<128>(A + (size_t)r0 * 512 + k0, 512, As, tid);
        stage64<128>(W + (size_t)c0 * 512 + k0, 512, Bs, tid);
        __syncthreads();
#pragma unroll
        for (int ks = 0; ks < 2; ks++) {
            f16x8 a[4], b[4];
#pragma unroll
            for (int i = 0; i < 4; i++) {
                a[i] = ldfrag(As, wM + i * 16 + lrow, ks * 4 + kq);
                b[i] = ldfrag(Bs, wN + i * 16 + lrow, ks * 4 + kq);
            }
#pragma unroll
            for (int mi = 0; mi < 4; mi++)
#pragma unroll
                for (int ni = 0; ni < 4; ni++)
                    acc[mi][ni] = mfma16(a[mi], b[ni], acc[mi][ni]);
        }
        __syncthreads();
    }
#pragma unroll
    for (int ni = 0; ni < 4; ni++) {
        const int col = c0 + wN + ni * 16 + lrow;
        const float bv = bias[col];
#pragma unroll
        for (int mi = 0; mi < 4; mi++) {
            const int row = r0 + wM + mi * 16 + kq * 4;
#pragma unroll
            for (int r = 0; r < 4; r++)
                q[(size_t)(row + r) * 512 + col] = (_Float16)(acc[mi][ni][r] + bv);
        }
    }
}

// ---------------- K2: S = q @ in2^T -> fp16 logits ---------------------------
__global__ __launch_bounds__(256, 4) void k_scores16(
    const _Float16* __restrict__ q, const _Float16* __restrict__ k,
    _Float16* __restrict__ S)
{
    __shared__ __align__(16) _Float16 As[128 * 64], Bs[128 * 64];
    const int tid = threadIdx.x;
    const int lane = tid & 63, wave = tid >> 6;
    const int wM = (wave >> 1) * 64, wN = (wave & 1) * 64;
    const int lrow = lane & 15, kq = lane >> 4;
    const int bi = blockIdx.x;
    const int bz = bi & 3, t = bi >> 2;       // low bits = batch -> XCD locality
    const int c0 = (t & 15) * 128, r0 = (t >> 4) * 128;
    const _Float16* qp = q + (size_t)bz * 2048 * 512;
    const _Float16* kp = k + (size_t)bz * 2048 * 512;
    _Float16* Sp = S + (size_t)bz * 2048 * 2048;

    floatx4 acc[4][4];
#pragma unroll
    for (int i = 0; i < 4; i++)
#pragma unroll
        for (int j = 0; j < 4; j++) acc[i][j] = (floatx4){0.f, 0.f, 0.f, 0.f};

    for (int k0 = 0; k0 < 512; k0 += 64) {
        stage64<128>(qp + (size_t)r0 * 512 + k0, 512, As, tid);
        stage64<128>(kp + (size_t)c0 * 512 + k0, 512, Bs, tid);
        __syncthreads();
#pragma unroll
        for (int ks = 0; ks < 2; ks++) {
            f16x8 a[4], b[4];
#pragma unroll
            for (int i = 0; i < 4; i++) {
                a[i] = ldfrag(As, wM + i * 16 + lrow, ks * 4 + kq);
                b[i] = ldfrag(Bs, wN + i * 16 + lrow, ks * 4 + kq);
            }
#pragma unroll
            for (int mi = 0; mi < 4; mi++)
#pragma unroll
                for (int ni = 0; ni < 4; ni++)
                    acc[mi][ni] = mfma16(a[mi], b[ni], acc[mi][ni]);
        }
        __syncthreads();
    }
#pragma unroll
    for (int mi = 0; mi < 4; mi++)
#pragma unroll
        for (int ni = 0; ni < 4; ni++) {
            const int row = r0 + wM + mi * 16 + kq * 4;
            const int col = c0 + wN + ni * 16 + lrow;
            _Float16* dst = Sp + (size_t)row * 2048 + col;
#pragma unroll
            for (int r = 0; r < 4; r++) dst[(size_t)r * 2048] = (_Float16)acc[mi][ni][r];
        }
}

// ---------------- K3: row softmax, fp16 in, fp16 out -------------------------
__global__ __launch_bounds__(256) void k_softmax(const _Float16* __restrict__ S,
                                                 _Float16* __restrict__ P)
{
    const int row = blockIdx.x;
    const _Float16* s = S + (size_t)row * 2048;
    _Float16* p = P + (size_t)row * 2048;
    const int tid = threadIdx.x;
    const int lane = tid & 63, wave = tid >> 6;

    F8 raw;
    raw.v = *(const f16x8*)(s + tid * 8);
    float v[8];
#pragma unroll
    for (int i = 0; i < 8; i++) v[i] = (float)raw.h[i];
    float m = fmaxf(fmaxf(fmaxf(v[0], v[1]), fmaxf(v[2], v[3])),
                    fmaxf(fmaxf(v[4], v[5]), fmaxf(v[6], v[7])));
#pragma unroll
    for (int off = 32; off >= 1; off >>= 1) m = fmaxf(m, __shfl_down(m, off));
    __shared__ float rb[4];
    if (lane == 0) rb[wave] = m;
    __syncthreads();
    m = fmaxf(fmaxf(rb[0], rb[1]), fmaxf(rb[2], rb[3]));

    float e[8];
#pragma unroll
    for (int i = 0; i < 8; i++) e[i] = __expf(v[i] - m);
    float sum = ((e[0] + e[1]) + (e[2] + e[3])) + ((e[4] + e[5]) + (e[6] + e[7]));
#pragma unroll
    for (int off = 32; off >= 1; off >>= 1) sum += __shfl_down(sum, off);
    __syncthreads();
    if (lane == 0) rb[wave] = sum;
    __syncthreads();
    const float inv = 1.0f / (((rb[0] + rb[1]) + (rb[2] + rb[3])));

    F8 w;
#pragma unroll
    for (int i = 0; i < 8; i++) w.h[i] = (_Float16)(e[i] * inv);
    *(f16x8*)(p + tid * 8) = w.v;
}

// ---------------- K4: out1 = P @ in2  (BM64 x BN128 x BK64) ------------------
__global__ __launch_bounds__(256, 4) void k_out1(
    const _Float16* __restrict__ P, const _Float16* __restrict__ Vt,
    float* __restrict__ O)
{
    __shared__ __align__(16) _Float16 As[64 * 64], Bs[128 * 64];
    const int tid = threadIdx.x;
    const int lane = tid & 63, wave = tid >> 6;
    const int wM = (wave >> 1) * 32, wN = (wave & 1) * 64;  // 2x2 waves: 32m x 64n
    const int lrow = lane & 15, kq = lane >> 4;
    const int bi = blockIdx.x;
    const int bz = bi & 7, t = bi >> 3;        // low bits = batch -> XCD locality
    const int c0 = (t & 3) * 128, r0 = (t >> 2) * 64;
    const _Float16* Pp = P + (size_t)bz * 2048 * 2048;
    const _Float16* Vp = Vt + (size_t)bz * 512 * 2048;
    float* Op = O + (size_t)bz * 2048 * 512;

    floatx4 acc[2][4];
#pragma unroll
    for (int i = 0; i < 2; i++)
#pragma unroll
        for (int j = 0; j < 4; j++) acc[i][j] = (floatx4){0.f, 0.f, 0.f, 0.f};

    for (int k0 = 0; k0 < 2048; k0 += 64) {
        stage64<64>(Pp + (size_t)r0 * 2048 + k0, 2048, As, tid);
        stage64<128>(Vp + (size_t)c0 * 2048 + k0, 2048, Bs, tid);
        __syncthreads();
#pragma unroll
        for (int ks = 0; ks < 2; ks++) {
            f16x8 a[2], b[4];
#pragma unroll
            for (int i = 0; i < 2; i++) a[i] = ldfrag(As, wM + i * 16 + lrow, ks * 4 + kq);
#pragma unroll
            for (int i = 0; i < 4; i++) b[i] = ldfrag(Bs, wN + i * 16 + lrow, ks * 4 + kq);
#pragma unroll
            for (int mi = 0; mi < 2; mi++)
#pragma unroll
                for (int ni = 0; ni < 4; ni++)
                    acc[mi][ni] = mfma16(a[mi], b[ni], acc[mi][ni]);
        }
        __syncthreads();
    }
#pragma unroll
    for (int mi = 0; mi < 2; mi++)
#pragma unroll
        for (int ni = 0; ni < 4; ni++) {
            const int row = r0 + wM + mi * 16 + kq * 4;
            const int col = c0 + wN + ni * 16 + lrow;
            float* dst = Op + (size_t)row * 512 + col;
#pragma unroll
            for (int r = 0; r < 4; r++) dst[(size_t)r * 512] = acc[mi][ni][r];
        }
}

// ---------------- K5: out2 = P^T @ in1 (A transpose-staged) ------------------
#define ASTR 72  // padded stride (halves) for transposed A tile
__global__ __launch_bounds__(256, 4) void k_out2(
    const _Float16* __restrict__ P, const _Float16* __restrict__ Xt,
    float* __restrict__ O)
{
    __shared__ __align__(16) _Float16 As[64 * ASTR];
    __shared__ __align__(16) _Float16 Bs[128 * 64];
    const int tid = threadIdx.x;
    const int lane = tid & 63, wave = tid >> 6;
    const int wM = (wave >> 1) * 32, wN = (wave & 1) * 64;
    const int lrow = lane & 15, kq = lane >> 4;
    const int bi = blockIdx.x;
    const int bz = bi & 7, t = bi >> 3;
    const int c0 = (t & 3) * 128, r0 = (t >> 2) * 64;   // r0 = key rows m
    const _Float16* Pp = P + (size_t)bz * 2048 * 2048;
    const _Float16* Xp = Xt + (size_t)bz * 512 * 2048;
    float* Op = O + (size_t)bz * 2048 * 512;

    const int mPair = (tid & 31) * 2;          // m column pair within tile
    const int kOct = tid >> 5;                 // k-oct (8 groups of 8)
    const int aswz = (kOct ^ (tid & 7)) << 3;  // (mPair>>1)&7 == tid&7

    floatx4 acc[2][4];
#pragma unroll
    for (int i = 0; i < 2; i++)
#pragma unroll
        for (int j = 0; j < 4; j++) acc[i][j] = (floatx4){0.f, 0.f, 0.f, 0.f};

    for (int k0 = 0; k0 < 2048; k0 += 64) {
        stage64<128>(Xp + (size_t)c0 * 2048 + k0, 2048, Bs, tid);
        {   // A: transpose-stage P[k][m] -> As[m][k], swizzled oct
            F8 w0, w1;
#pragma unroll
            for (int j = 0; j < 8; j++) {
                const unsigned g = *(const unsigned*)(
                    Pp + (size_t)(k0 + kOct * 8 + j) * 2048 + r0 + mPair);
                w0.u[j] = (unsigned short)(g & 0xffffu);
                w1.u[j] = (unsigned short)(g >> 16);
            }
            *(f16x8*)&As[mPair * ASTR + aswz] = w0.v;
            *(f16x8*)&As[(mPair + 1) * ASTR + aswz] = w1.v;
        }
        __syncthreads();
#pragma unroll
        for (int ks = 0; ks < 2; ks++) {
            f16x8 a[2], b[4];
#pragma unroll
            for (int i = 0; i < 2; i++) {
                const int m = wM + i * 16 + lrow;
                a[i] = *(const f16x8*)&As[m * ASTR +
                                          (((ks * 4 + kq) ^ ((m >> 1) & 7)) << 3)];
            }
#pragma unroll
            for (int i = 0; i < 4; i++) b[i] = ldfrag(Bs, wN + i * 16 + lrow, ks * 4 + kq);
#pragma unroll
            for (int mi = 0; mi < 2; mi++)
#pragma unroll
                for (int ni = 0; ni < 4; ni++)
                    acc[mi][ni] = mfma16(a[mi], b[ni], acc[mi][ni]);
        }
        __syncthreads();
    }
#pragma unroll
    for (int mi = 0; mi < 2; mi++)
#pragma unroll
        for (int ni = 0; ni < 4; ni++) {
            const int row = r0 + wM + mi * 16 + kq * 4;
            const int col = c0 + wN + ni * 16 + lrow;
            float* dst = Op + (size_t)row * 512 + col;
#pragma unroll
            for (int r = 0; r < 4; r++) dst[(size_t)r * 512] = acc[mi][ni][r];
        }
}

extern "C" void kernel_launch(void* const* d_in, const int* in_sizes, int n_in,
                              void* d_out, int out_size, void* d_ws, size_t ws_size,
                              hipStream_t stream)
{
    (void)in_sizes; (void)n_in; (void)out_size; (void)ws_size;
    const float* in1 = (const float*)d_in[0];
    const float* in2 = (const float*)d_in[1];
    const float* Ww  = (const float*)d_in[2];
    const float* Wb  = (const float*)d_in[3];
    float* out = (float*)d_out;

    char* ws = (char*)d_ws;
    _Float16* S   = (_Float16*)ws;                       // 32 MiB (fp16, half-batch)
    _Float16* P   = (_Float16*)(ws + 33554432ull);       // 64 MiB
    _Float16* q16 = (_Float16*)(ws + 100663296ull);      // 16 MiB
    _Float16* x16 = (_Float16*)(ws + 117440512ull);      // 16 MiB
    _Float16* k16 = (_Float16*)(ws + 134217728ull);      // 16 MiB
    _Float16* vt  = (_Float16*)(ws + 150994944ull);      // 16 MiB
    _Float16* xt  = (_Float16*)(ws + 167772160ull);      // 16 MiB
    _Float16* w16 = (_Float16*)(ws + 184549376ull);      // 0.5 MiB

    k_prep<<<dim3(4, 64, 8), 256, 0, stream>>>(in1, x16, xt);
    k_prep<<<dim3(4, 64, 8), 256, 0, stream>>>(in2, k16, vt);
    k_cvt <<<128, 256, 0, stream>>>(Ww, w16);
    k_qgemm16<<<512, 256, 0, stream>>>(x16, w16, Wb, q16);
    for (int h = 0; h < 2; h++) {
        k_scores16<<<1024, 256, 0, stream>>>(
            q16 + (size_t)h * 4 * 2048 * 512, k16 + (size_t)h * 4 * 2048 * 512, S);
        k_softmax<<<8192, 256, 0, stream>>>(S, P + (size_t)h * 4 * 2048 * 2048);
    }
    k_out1<<<1024, 256, 0, stream>>>(P, vt, out);
    k_out2<<<1024, 256, 0, stream>>>(P, xt, out + 8388608);
}

// Round 5
// 291.779 us; speedup vs baseline: 1.6613x; 1.0792x over previous
//
#include <hip/hip_runtime.h>

// CrossAttention B=8, N1=N2=2048, D=512 — all-fp16 MFMA pipeline, R5.
//  prep : in1 -> x16,xt ; in2 -> k16,vt      (one merged dispatch)
//  q    = in1 @ W^T + b   (fp16 MFMA, BK=64) -> q16
//  S    = q @ in2^T       (fp16 MFMA)        -> fp16 logits, FULL batch (64 MiB)
//  P    = softmax(S)      (fp32 math)        -> fp16, one dispatch
//  out1/out2               one 2048-block dispatch, BM64xBN128xBK128
// R4 post-mortem: out-kernels drain-bound (all pipes <33%). BK=128 halves the
// number of vmcnt(0)+barrier drains (32->16) with 2x MFMA per drain; 50 KB LDS
// -> 3 blocks/CU (m97's operating point; m132's BK128 regression was at 2).

typedef _Float16 f16x8 __attribute__((ext_vector_type(8)));
typedef float floatx4 __attribute__((ext_vector_type(4)));
typedef __attribute__((address_space(1))) const void* gptr_t;
typedef __attribute__((address_space(3))) void* lptr_t;

union F8 { f16x8 v; _Float16 h[8]; unsigned short u[8]; unsigned w[4]; };

__device__ __forceinline__ void gld16(const void* g, void* l) {
    __builtin_amdgcn_global_load_lds((gptr_t)g, (lptr_t)l, 16, 0, 0);
}
__device__ __forceinline__ floatx4 mfma16(f16x8 a, f16x8 b, floatx4 c) {
    return __builtin_amdgcn_mfma_f32_16x16x32_f16(a, b, c, 0, 0, 0);
}

// ---- BK=64 tiles: XOR swizzle over 8 octs (oct ^= row&7) --------------------
template <int ROWS>
__device__ __forceinline__ void stage64(const _Float16* g, int ldg,
                                        _Float16* lds, int tid) {
#pragma unroll
    for (int c = 0; c < (ROWS * 8) / 256; ++c) {
        const int q = c * 256 + tid;
        const int row = q >> 3;
        const int oct = (q & 7) ^ (row & 7);
        gld16(g + (size_t)row * ldg + oct * 8, lds + q * 8);
    }
}
__device__ __forceinline__ f16x8 ldfrag64(const _Float16* lds, int row, int j) {
    return *(const f16x8*)&lds[row * 64 + ((j ^ (row & 7)) << 3)];
}

// ---- BK=128 tiles: XOR swizzle over 16 octs (oct ^= row&15) -----------------
template <int ROWS>
__device__ __forceinline__ void stage128(const _Float16* g, int ldg,
                                         _Float16* lds, int tid) {
#pragma unroll
    for (int c = 0; c < (ROWS * 16) / 256; ++c) {
        const int q = c * 256 + tid;
        const int row = q >> 4;
        const int oct = (q & 15) ^ (row & 15);
        gld16(g + (size_t)row * ldg + oct * 8, lds + q * 8);
    }
}
__device__ __forceinline__ f16x8 ldfrag128(const _Float16* lds, int row, int j) {
    return *(const f16x8*)&lds[row * 128 + ((j ^ (row & 15)) << 3)];
}

// ---------------- prep: fp32 [b][n][512] -> row fp16 + col fp16 (merged) -----
__global__ __launch_bounds__(256) void k_prep2(
    const float* __restrict__ in1, const float* __restrict__ in2,
    _Float16* __restrict__ x16, _Float16* __restrict__ xt,
    _Float16* __restrict__ k16, _Float16* __restrict__ vt)
{
    const int z = blockIdx.z;
    const int b = z & 7;
    const float* src = (z < 8 ? in1 : in2);
    _Float16* rowo = (z < 8 ? x16 : k16);
    _Float16* colo = (z < 8 ? xt : vt);
    const int d0 = blockIdx.x * 128, n0 = blockIdx.y * 32;
    const float* Sp = src + (size_t)b * 2048 * 512;
    _Float16* Rp = rowo + (size_t)b * 2048 * 512;
    _Float16* Cp = colo + (size_t)b * 512 * 2048;
    const int t = threadIdx.x, i = t & 63, jn = t >> 6;
    const int d = d0 + 2 * i, n = n0 + jn * 8;
    F8 w0, w1;
#pragma unroll
    for (int j = 0; j < 8; j++) {
        float2 g = *(const float2*)(Sp + (size_t)(n + j) * 512 + d);
        w0.h[j] = (_Float16)g.x; w1.h[j] = (_Float16)g.y;
        F8 r; r.h[0] = w0.h[j]; r.h[1] = w1.h[j];
        *(unsigned*)(Rp + (size_t)(n + j) * 512 + d) = r.w[0];
    }
    *(f16x8*)(Cp + (size_t)d * 2048 + n) = w0.v;
    *(f16x8*)(Cp + (size_t)(d + 1) * 2048 + n) = w1.v;
}

// ---------------- prep: fp32 -> fp16 elementwise (for W) ---------------------
__global__ __launch_bounds__(256) void k_cvt(const float* __restrict__ src,
                                             _Float16* __restrict__ dst)
{
    const size_t i = ((size_t)blockIdx.x * 256 + threadIdx.x) * 8;
    float4 a = *(const float4*)(src + i);
    float4 b = *(const float4*)(src + i + 4);
    F8 w;
    w.h[0] = (_Float16)a.x; w.h[1] = (_Float16)a.y;
    w.h[2] = (_Float16)a.z; w.h[3] = (_Float16)a.w;
    w.h[4] = (_Float16)b.x; w.h[5] = (_Float16)b.y;
    w.h[6] = (_Float16)b.z; w.h[7] = (_Float16)b.w;
    *(f16x8*)(dst + i) = w.v;
}

// ---------------- K1: q = in1 @ W^T + bias (128x128, BK=64) ------------------
__global__ __launch_bounds__(256, 4) void k_qgemm16(
    const _Float16* __restrict__ A, const _Float16* __restrict__ W,
    const float* __restrict__ bias, _Float16* __restrict__ q)
{
    __shared__ __align__(16) _Float16 As[128 * 64], Bs[128 * 64];
    const int tid = threadIdx.x;
    const int lane = tid & 63, wave = tid >> 6;
    const int wM = (wave >> 1) * 64, wN = (wave & 1) * 64;
    const int lrow = lane & 15, kq = lane >> 4;
    const int bi = blockIdx.x;
    const int r0 = (bi >> 2) * 128, c0 = (bi & 3) * 128;

    floatx4 acc[4][4];
#pragma unroll
    for (int i = 0; i < 4; i++)
#pragma unroll
        for (int j = 0; j < 4; j++) acc[i][j] = (floatx4){0.f, 0.f, 0.f, 0.f};

    for (int k0 = 0; k0 < 512; k0 += 64) {
        stage64<128>(A + (size_t)r0 * 512 + k0, 512, As, tid);
        stage64<128>(W + (size_t)c0 * 512 + k0, 512, Bs, tid);
        __syncthreads();
#pragma unroll
        for (int ks = 0; ks < 2; ks++) {
            f16x8 a[4], b[4];
#pragma unroll
            for (int i = 0; i < 4; i++) {
                a[i] = ldfrag64(As, wM + i * 16 + lrow, ks * 4 + kq);
                b[i] = ldfrag64(Bs, wN + i * 16 + lrow, ks * 4 + kq);
            }
#pragma unroll
            for (int mi = 0; mi < 4; mi++)
#pragma unroll
                for (int ni = 0; ni < 4; ni++)
                    acc[mi][ni] = mfma16(a[mi], b[ni], acc[mi][ni]);
        }
        __syncthreads();
    }
#pragma unroll
    for (int ni = 0; ni < 4; ni++) {
        const int col = c0 + wN + ni * 16 + lrow;
        const float bv = bias[col];
#pragma unroll
        for (int mi = 0; mi < 4; mi++) {
            const int row = r0 + wM + mi * 16 + kq * 4;
#pragma unroll
            for (int r = 0; r < 4; r++)
                q[(size_t)(row + r) * 512 + col] = (_Float16)(acc[mi][ni][r] + bv);
        }
    }
}

// ---------------- K2: S = q @ in2^T -> fp16 logits (full batch) --------------
__global__ __launch_bounds__(256, 4) void k_scores16(
    const _Float16* __restrict__ q, const _Float16* __restrict__ k,
    _Float16* __restrict__ S)
{
    __shared__ __align__(16) _Float16 As[128 * 64], Bs[128 * 64];
    const int tid = threadIdx.x;
    const int lane = tid & 63, wave = tid >> 6;
    const int wM = (wave >> 1) * 64, wN = (wave & 1) * 64;
    const int lrow = lane & 15, kq = lane >> 4;
    const int bi = blockIdx.x;
    const int bz = bi & 7, t = bi >> 3;       // low bits = batch -> XCD locality
    const int c0 = (t & 15) * 128, r0 = (t >> 4) * 128;
    const _Float16* qp = q + (size_t)bz * 2048 * 512;
    const _Float16* kp = k + (size_t)bz * 2048 * 512;
    _Float16* Sp = S + (size_t)bz * 2048 * 2048;

    floatx4 acc[4][4];
#pragma unroll
    for (int i = 0; i < 4; i++)
#pragma unroll
        for (int j = 0; j < 4; j++) acc[i][j] = (floatx4){0.f, 0.f, 0.f, 0.f};

    for (int k0 = 0; k0 < 512; k0 += 64) {
        stage64<128>(qp + (size_t)r0 * 512 + k0, 512, As, tid);
        stage64<128>(kp + (size_t)c0 * 512 + k0, 512, Bs, tid);
        __syncthreads();
#pragma unroll
        for (int ks = 0; ks < 2; ks++) {
            f16x8 a[4], b[4];
#pragma unroll
            for (int i = 0; i < 4; i++) {
                a[i] = ldfrag64(As, wM + i * 16 + lrow, ks * 4 + kq);
                b[i] = ldfrag64(Bs, wN + i * 16 + lrow, ks * 4 + kq);
            }
#pragma unroll
            for (int mi = 0; mi < 4; mi++)
#pragma unroll
                for (int ni = 0; ni < 4; ni++)
                    acc[mi][ni] = mfma16(a[mi], b[ni], acc[mi][ni]);
        }
        __syncthreads();
    }
#pragma unroll
    for (int mi = 0; mi < 4; mi++)
#pragma unroll
        for (int ni = 0; ni < 4; ni++) {
            const int row = r0 + wM + mi * 16 + kq * 4;
            const int col = c0 + wN + ni * 16 + lrow;
            _Float16* dst = Sp + (size_t)row * 2048 + col;
#pragma unroll
            for (int r = 0; r < 4; r++) dst[(size_t)r * 2048] = (_Float16)acc[mi][ni][r];
        }
}

// ---------------- K3: row softmax, fp16 in, fp16 out -------------------------
__global__ __launch_bounds__(256) void k_softmax(const _Float16* __restrict__ S,
                                                 _Float16* __restrict__ P)
{
    const int row = blockIdx.x;
    const _Float16* s = S + (size_t)row * 2048;
    _Float16* p = P + (size_t)row * 2048;
    const int tid = threadIdx.x;
    const int lane = tid & 63, wave = tid >> 6;

    F8 raw;
    raw.v = *(const f16x8*)(s + tid * 8);
    float v[8];
#pragma unroll
    for (int i = 0; i < 8; i++) v[i] = (float)raw.h[i];
    float m = fmaxf(fmaxf(fmaxf(v[0], v[1]), fmaxf(v[2], v[3])),
                    fmaxf(fmaxf(v[4], v[5]), fmaxf(v[6], v[7])));
#pragma unroll
    for (int off = 32; off >= 1; off >>= 1) m = fmaxf(m, __shfl_down(m, off));
    __shared__ float rb[4];
    if (lane == 0) rb[wave] = m;
    __syncthreads();
    m = fmaxf(fmaxf(rb[0], rb[1]), fmaxf(rb[2], rb[3]));

    float e[8];
#pragma unroll
    for (int i = 0; i < 8; i++) e[i] = __expf(v[i] - m);
    float sum = ((e[0] + e[1]) + (e[2] + e[3])) + ((e[4] + e[5]) + (e[6] + e[7]));
#pragma unroll
    for (int off = 32; off >= 1; off >>= 1) sum += __shfl_down(sum, off);
    __syncthreads();
    if (lane == 0) rb[wave] = sum;
    __syncthreads();
    const float inv = 1.0f / (((rb[0] + rb[1]) + (rb[2] + rb[3])));

    F8 w;
#pragma unroll
    for (int i = 0; i < 8; i++) w.h[i] = (_Float16)(e[i] * inv);
    *(f16x8*)(p + tid * 8) = w.v;
}

// ---------------- K4: out1 & out2 merged, BM64 x BN128 x BK128 ---------------
// blocks [0,1024):   out1 = P @ Vt^T-layout   (A = P rows, direct gld16)
// blocks [1024,2048): out2 = P^T @ Xt^T-layout (A = P reg-transposed)
#define ASTR 136  // padded stride (halves) for transposed A tile (BK=128 + 8)
__global__ __launch_bounds__(256, 3) void k_out12(
    const _Float16* __restrict__ P, const _Float16* __restrict__ Vt,
    const _Float16* __restrict__ Xt, float* __restrict__ O1,
    float* __restrict__ O2)
{
    __shared__ __align__(16) _Float16 As[64 * ASTR];   // out1 uses 64*128 of it
    __shared__ __align__(16) _Float16 Bs[128 * 128];
    const int tid = threadIdx.x;
    const int lane = tid & 63, wave = tid >> 6;
    const int wM = (wave >> 1) * 32, wN = (wave & 1) * 64;
    const int lrow = lane & 15, kq = lane >> 4;
    const bool isO2 = blockIdx.x >= 1024;
    const int bi = blockIdx.x & 1023;
    const int bz = bi & 7, t = bi >> 3;        // low bits = batch -> XCD locality
    const int c0 = (t & 3) * 128, r0 = (t >> 2) * 64;
    const _Float16* Pp = P + (size_t)bz * 2048 * 2048;
    const _Float16* Bp = (isO2 ? Xt : Vt) + (size_t)bz * 512 * 2048;
    float* Op = (isO2 ? O2 : O1) + (size_t)bz * 2048 * 512;

    floatx4 acc[2][4];
#pragma unroll
    for (int i = 0; i < 2; i++)
#pragma unroll
        for (int j = 0; j < 4; j++) acc[i][j] = (floatx4){0.f, 0.f, 0.f, 0.f};

    if (!isO2) {
        for (int k0 = 0; k0 < 2048; k0 += 128) {
            stage128<64>(Pp + (size_t)r0 * 2048 + k0, 2048, As, tid);
            stage128<128>(Bp + (size_t)c0 * 2048 + k0, 2048, Bs, tid);
            __syncthreads();
#pragma unroll
            for (int ks = 0; ks < 4; ks++) {
                f16x8 a[2], b[4];
#pragma unroll
                for (int i = 0; i < 2; i++)
                    a[i] = ldfrag128(As, wM + i * 16 + lrow, ks * 4 + kq);
#pragma unroll
                for (int i = 0; i < 4; i++)
                    b[i] = ldfrag128(Bs, wN + i * 16 + lrow, ks * 4 + kq);
#pragma unroll
                for (int mi = 0; mi < 2; mi++)
#pragma unroll
                    for (int ni = 0; ni < 4; ni++)
                        acc[mi][ni] = mfma16(a[mi], b[ni], acc[mi][ni]);
            }
            __syncthreads();
        }
    } else {
        const int mPair = (tid & 31) * 2;   // m column pair within 64-tile
        const int kOct0 = tid >> 5;         // base k-oct
        for (int k0 = 0; k0 < 2048; k0 += 128) {
            stage128<128>(Bp + (size_t)c0 * 2048 + k0, 2048, Bs, tid);
#pragma unroll
            for (int kh = 0; kh < 2; kh++) {  // A: transpose P[k][m] -> As[m][k]
                const int kOct = kOct0 + kh * 8;
                F8 w0, w1;
#pragma unroll
                for (int j = 0; j < 8; j++) {
                    const unsigned g = *(const unsigned*)(
                        Pp + (size_t)(k0 + kOct * 8 + j) * 2048 + r0 + mPair);
                    w0.u[j] = (unsigned short)(g & 0xffffu);
                    w1.u[j] = (unsigned short)(g >> 16);
                }
                *(f16x8*)&As[mPair * ASTR + kOct * 8] = w0.v;
                *(f16x8*)&As[(mPair + 1) * ASTR + kOct * 8] = w1.v;
            }
            __syncthreads();
#pragma unroll
            for (int ks = 0; ks < 4; ks++) {
                f16x8 a[2], b[4];
#pragma unroll
                for (int i = 0; i < 2; i++)
                    a[i] = *(const f16x8*)&As[(wM + i * 16 + lrow) * ASTR +
                                              (ks * 4 + kq) * 8];
#pragma unroll
                for (int i = 0; i < 4; i++)
                    b[i] = ldfrag128(Bs, wN + i * 16 + lrow, ks * 4 + kq);
#pragma unroll
                for (int mi = 0; mi < 2; mi++)
#pragma unroll
                    for (int ni = 0; ni < 4; ni++)
                        acc[mi][ni] = mfma16(a[mi], b[ni], acc[mi][ni]);
            }
            __syncthreads();
        }
    }
#pragma unroll
    for (int mi = 0; mi < 2; mi++)
#pragma unroll
        for (int ni = 0; ni < 4; ni++) {
            const int row = r0 + wM + mi * 16 + kq * 4;
            const int col = c0 + wN + ni * 16 + lrow;
            float* dst = Op + (size_t)row * 512 + col;
#pragma unroll
            for (int r = 0; r < 4; r++) dst[(size_t)r * 512] = acc[mi][ni][r];
        }
}

extern "C" void kernel_launch(void* const* d_in, const int* in_sizes, int n_in,
                              void* d_out, int out_size, void* d_ws, size_t ws_size,
                              hipStream_t stream)
{
    (void)in_sizes; (void)n_in; (void)out_size; (void)ws_size;
    const float* in1 = (const float*)d_in[0];
    const float* in2 = (const float*)d_in[1];
    const float* Ww  = (const float*)d_in[2];
    const float* Wb  = (const float*)d_in[3];
    float* out = (float*)d_out;

    char* ws = (char*)d_ws;
    _Float16* S   = (_Float16*)ws;                       // 64 MiB (fp16, full batch)
    _Float16* P   = (_Float16*)(ws + 67108864ull);       // 64 MiB
    _Float16* q16 = (_Float16*)(ws + 134217728ull);      // 16 MiB
    _Float16* x16 = (_Float16*)(ws + 150994944ull);      // 16 MiB
    _Float16* k16 = (_Float16*)(ws + 167772160ull);      // 16 MiB
    _Float16* vt  = (_Float16*)(ws + 184549376ull);      // 16 MiB
    _Float16* xt  = (_Float16*)(ws + 201326592ull);      // 16 MiB
    _Float16* w16 = (_Float16*)(ws + 218103808ull);      // 0.5 MiB

    k_prep2<<<dim3(4, 64, 16), 256, 0, stream>>>(in1, in2, x16, xt, k16, vt);
    k_cvt <<<128, 256, 0, stream>>>(Ww, w16);
    k_qgemm16<<<512, 256, 0, stream>>>(x16, w16, Wb, q16);
    k_scores16<<<2048, 256, 0, stream>>>(q16, k16, S);
    k_softmax<<<16384, 256, 0, stream>>>(S, P);
    k_out12<<<2048, 256, 0, stream>>>(P, vt, xt, out, out + 8388608);
}